// Round 17
// baseline (206.150 us; speedup 1.0000x reference)
//
#include <hip/hip_runtime.h>
#include <math.h>

#define NPTS 8192
#define NB   4
#define KNN  16
#define NC   64
#define NQ   (NB * NPTS)   // 32768 total queries
#define ECAP 21            // per-(wave,query) packed-entry capacity; stride 21
                           // is coprime with 32 banks -> conflict-free decode
#define ILCAP 128          // per-query decoded survivor idx capacity (u16,
                           // lives in a 132-u16 mxs row; E~30, P(ovfl)~1e-20)

// ---------------------------------------------------------------------------
// prep (2 phases as separate blocks) — unchanged (validated r2..r16):
//  phase 0 (source pts): cand[b][m]=(x,y,z,|p|^2); GF[b][m][o]=(Gk,F2)
//  phase 1 (center pts): CF[b][n][o]=(Gc+bg, F1+bf)
// ---------------------------------------------------------------------------
__global__ __launch_bounds__(256) void prep_kernel(
    const float* __restrict__ xyz, const float* __restrict__ xyz_s,
    const float* __restrict__ fea, const float* __restrict__ fea_s,
    const float* __restrict__ Wg,  const float* __restrict__ bg,
    const float* __restrict__ Wf,  const float* __restrict__ bf,
    float4* __restrict__ cand, float2* __restrict__ GF, float2* __restrict__ CF)
{
    __shared__ float wt[64 * 64];
    __shared__ float gw[3 * 64];
    __shared__ float bias2[2 * 64];
    int tid   = threadIdx.x;
    int phase = blockIdx.x & 1;
    int g     = (blockIdx.x >> 1) * 256 + tid;
    int b     = g >> 13, m = g & (NPTS - 1);

    for (int i = tid; i < 4096; i += 256) {
        int o = i >> 6, c = i & 63;
        wt[c * 64 + o] = Wf[o * 128 + (phase ? c : 64 + c)];
    }
    if (tid < 192) {
        int d = tid >> 6, o = tid & 63;
        gw[d * 64 + o] = phase ? (Wg[o * 10 + 1 + d] + Wg[o * 10 + 7 + d])
                               : (Wg[o * 10 + 4 + d] - Wg[o * 10 + 7 + d]);
    }
    if (tid < 64) {
        bias2[tid]      = phase ? bg[tid] : 0.f;
        bias2[64 + tid] = phase ? bf[tid] : 0.f;
    }
    __syncthreads();

    const float* P = phase ? xyz : xyz_s;
    const float* F = phase ? fea : fea_s;
    float x = P[(b * 3 + 0) * NPTS + m];
    float y = P[(b * 3 + 1) * NPTS + m];
    float z = P[(b * 3 + 2) * NPTS + m];
    if (!phase) cand[b * NPTS + m] = make_float4(x, y, z, x * x + y * y + z * z);

    float acc[NC];
    #pragma unroll
    for (int o = 0; o < NC; o++) acc[o] = 0.f;
    for (int c = 0; c < NC; c++) {
        float v = F[(size_t)(b * NC + c) * NPTS + m];
        const float4* w4 = (const float4*)&wt[c * 64];
        #pragma unroll
        for (int o4 = 0; o4 < 16; o4++) {
            float4 w = w4[o4];
            acc[o4*4+0] = fmaf(w.x, v, acc[o4*4+0]);
            acc[o4*4+1] = fmaf(w.y, v, acc[o4*4+1]);
            acc[o4*4+2] = fmaf(w.z, v, acc[o4*4+2]);
            acc[o4*4+3] = fmaf(w.w, v, acc[o4*4+3]);
        }
    }
    float2* O = (phase ? CF : GF) + ((size_t)(b * NPTS + m)) * NC;
    #pragma unroll
    for (int o = 0; o < NC; o++) {
        float geo = fmaf(gw[o], x, fmaf(gw[64 + o], y, gw[128 + o] * z));
        O[o] = make_float2(geo + bias2[o], acc[o] + bias2[64 + o]);
    }
}

// ---------------------------------------------------------------------------
// knn_fused5: tau + filter + select, candidate-stationary, 8 waves/block.
// [r16 post-mortem: A scored ALL 16 slots just for tau (~40% of kernel);
//  el stride 20 u32 -> 8-way bank conflict in decode (148K). Fix: (1) A
//  samples slots 0..7 only — 64 submaxima of DISJOINT 64-cand groups over
//  4096 cands; tau = 16th largest still has >=16 witnesses (same proof),
//  E[rank]~30; (2) el stride 21 (coprime 32) -> conflict-free; (3) decoded
//  idx list as u16[128] in the dead mxs row -> overflow risk gone.]
// Wave w owns cands [1024w,1024(w+1)); lane owns c[s]=cb[w*1024+s*64+lane].
//  A: dual-chain lane max over slots 0..7 -> shfl_xor(1,2,4) -> 64 submaxima.
//  T: tau = 16th largest of 64 (r9-validated bitonic) -> qt_lds[q].w.
//  B: branch-free u16 mask filter over ALL 16 slots (bit-identical fma),
//     ONE ballot per (wave,query), packed (lane<<16)|mask entries.
//  S: decode -> u16 idx list -> batch-4 gather + u64 sorted-insert -> idxb.
// Grid: NQ/64 = 512 blocks x 512 threads.
// ---------------------------------------------------------------------------
__global__ __launch_bounds__(512, 4) void knn_fused5(
    const float4* __restrict__ cand, const float* __restrict__ xyz,
    int* __restrict__ idxout)
{
    __shared__ float4 qt_lds[64];            // .w = tau after T
    __shared__ float  mxs[64][66];           // A/T: submaxima; S: u16 idx list
    __shared__ unsigned int  el[8][64][ECAP];
    __shared__ unsigned char ecnt[8][64];

    int tid = threadIdx.x;
    int lane = tid & 63, w = tid >> 6;       // w in 0..7
    int bid = blockIdx.x;
    int b = bid >> 7;                        // 128 blocks per batch
    int qb = (bid & 127) * 64;

    if (tid < 64) {
        int q = qb + tid;
        float x = xyz[(b * 3 + 0) * NPTS + q];
        float y = xyz[(b * 3 + 1) * NPTS + q];
        float z = xyz[(b * 3 + 2) * NPTS + q];
        qt_lds[tid] = make_float4(2.f * x, 2.f * y, 2.f * z, 0.f);
    }

    const float4* cb = cand + b * NPTS;
    int cbase = (w << 10) + lane;            // lane's cands: cbase + s*64
    float4 c[16];
    #pragma unroll
    for (int s = 0; s < 16; s++) c[s] = cb[cbase + (s << 6)];
    // residency force (r15-validated): compiler cannot re-load from memory
    #pragma unroll
    for (int s = 0; s < 16; s++)
        asm volatile("" : "+v"(c[s].x), "+v"(c[s].y), "+v"(c[s].z), "+v"(c[s].w));
    __syncthreads();

    // ---- A: sampled submaxima — slots 0..7 only (4096 cands, 64 disjoint
    //      64-cand groups). Dual-chain lane max + 8-lane shfl reduce. ----
    for (int qi = 0; qi < 64; ++qi) {
        float4 qt = qt_lds[qi];
        float M0 = -3.0e38f, M1 = -3.0e38f;
        #pragma unroll
        for (int s = 0; s < 8; s += 2) {
            float sc0 = fmaf(c[s].x, qt.x, fmaf(c[s].y, qt.y,
                        fmaf(c[s].z, qt.z, -c[s].w)));
            float sc1 = fmaf(c[s+1].x, qt.x, fmaf(c[s+1].y, qt.y,
                        fmaf(c[s+1].z, qt.z, -c[s+1].w)));
            M0 = fmaxf(M0, sc0);
            M1 = fmaxf(M1, sc1);
        }
        float gmx = fmaxf(M0, M1);
        gmx = fmaxf(gmx, __shfl_xor(gmx, 1));
        gmx = fmaxf(gmx, __shfl_xor(gmx, 2));
        gmx = fmaxf(gmx, __shfl_xor(gmx, 4));   // 8-lane group max (64 cands)
        if ((lane & 7) == 0) mxs[qi][(w << 3) + (lane >> 3)] = gmx;
    }
    __syncthreads();

    // ---- T: tau = 16th largest of 64 submaxima -> qt_lds[qq].w ----
    for (int qq = w * 8; qq < w * 8 + 8; ++qq) {
        float v = mxs[qq][lane];
        #pragma unroll
        for (int k = 2; k <= 64; k <<= 1) {
            #pragma unroll
            for (int j = k >> 1; j > 0; j >>= 1) {
                float o = __shfl_xor(v, j);
                bool up = ((lane & k) == 0);
                bool lower = ((lane & j) == 0);
                v = (up == lower) ? fminf(v, o) : fmaxf(v, o);
            }
        }
        float t = __shfl(v, 48);             // 16th largest (all lanes)
        if (lane == 0) qt_lds[qq].w = t;
    }
    __syncthreads();

    // ---- B: branch-free mask filter over ALL 16 slots; 1 ballot/query ----
    unsigned long long lmask = (1ull << lane) - 1ull;
    for (int qi = 0; qi < 64; ++qi) {
        float4 qt = qt_lds[qi];              // .w = tau
        unsigned msk = 0;
        #pragma unroll
        for (int s = 0; s < 16; s++) {
            float sc = fmaf(c[s].x, qt.x, fmaf(c[s].y, qt.y,
                       fmaf(c[s].z, qt.z, -c[s].w)));
            msk |= (sc >= qt.w) ? (1u << s) : 0u;
        }
        unsigned long long m = __ballot(msk != 0u);
        if (msk) {
            unsigned pos = (unsigned)__popcll(m & lmask);
            if (pos < ECAP)
                el[w][qi][pos] = ((unsigned)lane << 16) | msk;
        }
        if (lane == 0) {
            unsigned tot = (unsigned)__popcll(m);
            ecnt[w][qi] = (unsigned char)(tot < ECAP ? tot : ECAP);
        }
    }
    __syncthreads();

    // ---- S: decode entries -> u16 idx list (mxs row), then top-16 ----
    if (tid < 64) {
        int qi = tid;
        unsigned short* il = (unsigned short*)&mxs[qi][0];  // 132 u16 slots
        int cnt = 0;
        for (int w2 = 0; w2 < 8; w2++) {
            int cn = ecnt[w2][qi];
            for (int j = 0; j < cn; j++) {
                unsigned e = el[w2][qi][j];
                int base = (w2 << 10) + (int)(e >> 16);
                unsigned mk = e & 0xFFFFu;
                while (mk) {
                    int s = __builtin_ctz(mk);
                    mk &= mk - 1u;
                    if (cnt < ILCAP)
                        il[cnt++] = (unsigned short)(base + (s << 6));
                }
            }
        }

        float4 qt = qt_lds[qi];
        unsigned long long s16[KNN];
        #pragma unroll
        for (int j = 0; j < KNN; j++) s16[j] = 0ull;

        for (int j0 = 0; j0 < cnt; j0 += 4) {
            int li[4];
            float4 cd[4];
            #pragma unroll
            for (int t = 0; t < 4; t++) {
                int j = j0 + t;
                li[t] = (j < cnt) ? (int)il[j] : -1;
            }
            #pragma unroll
            for (int t = 0; t < 4; t++)
                if (li[t] >= 0) cd[t] = cb[li[t]];
            #pragma unroll
            for (int t = 0; t < 4; t++) {
                if (li[t] < 0) continue;
                float sc = fmaf(cd[t].x, qt.x, fmaf(cd[t].y, qt.y,
                           fmaf(cd[t].z, qt.z, -cd[t].w)));
                unsigned u = __float_as_uint(sc);
                u ^= (unsigned)((int)u >> 31) | 0x80000000u;
                unsigned long long key =
                    ((unsigned long long)u << 32) | (unsigned)(8191 - li[t]);
                if (key > s16[0]) {
                    bool cj = true;
                    #pragma unroll
                    for (int t2 = 0; t2 < KNN; t2++) {
                        bool cn2 = (t2 < KNN - 1) ? (key > s16[t2 + 1]) : false;
                        unsigned long long fv = cj ? key : s16[t2];
                        s16[t2] = cn2 ? s16[t2 + 1] : fv;
                        cj = cn2;
                    }
                }
            }
        }
        int* op = idxout + (((size_t)(b * NPTS + qb + qi)) << 4);
        #pragma unroll
        for (int j = 0; j < KNN; j++)
            op[j] = 8191 - (int)(s16[j] & 0xFFFFFFFFull);
    }
}

// ---------------------------------------------------------------------------
// fuse — unchanged (validated r2..r16):
// out[b][o][n] = max_k relu(CF.x + wd*d + GF.x) * relu(CF.y + GF.y)
// ---------------------------------------------------------------------------
__global__ __launch_bounds__(256) void fuse_kernel(
    const float* __restrict__ xyz, const float* __restrict__ Wg,
    const float4* __restrict__ cand, const float2* __restrict__ GF,
    const float2* __restrict__ CF, const int* __restrict__ idxb,
    float* __restrict__ out)
{
    __shared__ float tile[16 * 65];
    int tid = threadIdx.x;
    int o = tid & 63, w = tid >> 6;
    int b = blockIdx.x >> 9;
    int nt = (blockIdx.x & 511) << 4;
    float wd = Wg[o * 10];

    for (int i = 0; i < 4; i++) {
        int q = nt + w * 4 + i;
        size_t qb = (size_t)(b * NPTS + q);
        float qx = xyz[(b * 3 + 0) * NPTS + q];
        float qy = xyz[(b * 3 + 1) * NPTS + q];
        float qz = xyz[(b * 3 + 2) * NPTS + q];
        float2 cf = CF[qb * NC + o];
        const int* ip = idxb + qb * KNN;
        float r = 0.f;
        #pragma unroll 4
        for (int kk = 0; kk < KNN; kk++) {
            int mi = ip[kk];
            float4 c = cand[b * NPTS + mi];
            float dx = qx - c.x, dy = qy - c.y, dz = qz - c.z;
            float d = sqrtf(fmaf(dx, dx, fmaf(dy, dy, dz * dz)));
            float2 gf = GF[((size_t)(b * NPTS + mi)) * NC + o];
            float gpre = cf.x + fmaf(wd, d, gf.x);
            float fpre = cf.y + gf.y;
            r = fmaxf(r, fmaxf(gpre, 0.f) * fmaxf(fpre, 0.f));
        }
        tile[(w * 4 + i) * 65 + o] = r;
    }
    __syncthreads();
    int row = tid >> 2, cg = (tid & 3) * 4;
    float* orow = out + (size_t)(b * NC + row) * NPTS + nt + cg;
    #pragma unroll
    for (int j = 0; j < 4; j++) orow[j] = tile[(cg + j) * 65 + row];
}

extern "C" void kernel_launch(void* const* d_in, const int* in_sizes, int n_in,
                              void* d_out, int out_size, void* d_ws, size_t ws_size,
                              hipStream_t stream) {
    const float* xyz   = (const float*)d_in[0];
    const float* xyz_s = (const float*)d_in[1];
    const float* fea   = (const float*)d_in[2];
    const float* fea_s = (const float*)d_in[3];
    const float* Wg    = (const float*)d_in[4];
    const float* bg    = (const float*)d_in[5];
    const float* Wf    = (const float*)d_in[6];
    const float* bf    = (const float*)d_in[7];
    float* out = (float*)d_out;

    char* ws = (char*)d_ws;
    float4* cand = (float4*)ws;                 ws += (size_t)NQ * 16;      // 512 KB
    float2* GF   = (float2*)ws;                 ws += (size_t)NQ * NC * 8;  // 16.8 MB
    float2* CF   = (float2*)ws;                 ws += (size_t)NQ * NC * 8;  // 16.8 MB
    int*    idxb = (int*)ws;                                                // 2 MB

    prep_kernel<<<(NQ / 256) * 2, 256, 0, stream>>>(
        xyz, xyz_s, fea, fea_s, Wg, bg, Wf, bf, cand, GF, CF);
    knn_fused5<<<NQ / 64, 512, 0, stream>>>(cand, xyz, idxb);
    fuse_kernel<<<NB * (NPTS / 16), 256, 0, stream>>>(
        xyz, Wg, cand, GF, CF, idxb, out);
}

// Round 18
// 188.513 us; speedup vs baseline: 1.0936x; 1.0936x over previous
//
#include <hip/hip_runtime.h>
#include <math.h>

#define NPTS 8192
#define NB   4
#define KNN  16
#define NC   64
#define NQ   (NB * NPTS)   // 32768 total queries
#define ECAP 20            // per-(wave,query) packed-entry capacity (E~2.7)
#define ILCAP 66           // per-query decoded survivor idx capacity (E~22)

// ---------------------------------------------------------------------------
// prep (2 phases as separate blocks), 64-thread / 64-point blocks:
//  phase 0 (source pts): cand[b][m]=(x,y,z,|p|^2); GF[b][m][o]=(Gk,F2)
//  phase 1 (center pts): CF[b][n][o]=(Gc+bg, F1+bf)
// [r17 post-mortem: prep was GRID-limited — 256 blocks = 1 block/CU = 1
//  wave/SIMD, so the per-wave serial chain of 1024 broadcast ds_read_b128
//  (~12K cyc LDS issue) had zero overlap. 64-thr/64-pt blocks -> grid 2048
//  -> 8 blocks/CU = 2 waves/SIMD; per-thread work and arithmetic identical.]
// ---------------------------------------------------------------------------
__global__ __launch_bounds__(64) void prep_kernel(
    const float* __restrict__ xyz, const float* __restrict__ xyz_s,
    const float* __restrict__ fea, const float* __restrict__ fea_s,
    const float* __restrict__ Wg,  const float* __restrict__ bg,
    const float* __restrict__ Wf,  const float* __restrict__ bf,
    float4* __restrict__ cand, float2* __restrict__ GF, float2* __restrict__ CF)
{
    __shared__ float wt[64 * 64];
    __shared__ float gw[3 * 64];
    __shared__ float bias2[2 * 64];
    int tid   = threadIdx.x;
    int phase = blockIdx.x & 1;
    int g     = (blockIdx.x >> 1) * 64 + tid;
    int b     = g >> 13, m = g & (NPTS - 1);

    for (int i = tid; i < 4096; i += 64) {
        int o = i >> 6, c = i & 63;
        wt[c * 64 + o] = Wf[o * 128 + (phase ? c : 64 + c)];
    }
    for (int i = tid; i < 192; i += 64) {
        int d = i >> 6, o = i & 63;
        gw[d * 64 + o] = phase ? (Wg[o * 10 + 1 + d] + Wg[o * 10 + 7 + d])
                               : (Wg[o * 10 + 4 + d] - Wg[o * 10 + 7 + d]);
    }
    {
        bias2[tid]      = phase ? bg[tid] : 0.f;
        bias2[64 + tid] = phase ? bf[tid] : 0.f;
    }
    __syncthreads();

    const float* P = phase ? xyz : xyz_s;
    const float* F = phase ? fea : fea_s;
    float x = P[(b * 3 + 0) * NPTS + m];
    float y = P[(b * 3 + 1) * NPTS + m];
    float z = P[(b * 3 + 2) * NPTS + m];
    if (!phase) cand[b * NPTS + m] = make_float4(x, y, z, x * x + y * y + z * z);

    float acc[NC];
    #pragma unroll
    for (int o = 0; o < NC; o++) acc[o] = 0.f;
    for (int c = 0; c < NC; c++) {
        float v = F[(size_t)(b * NC + c) * NPTS + m];
        const float4* w4 = (const float4*)&wt[c * 64];
        #pragma unroll
        for (int o4 = 0; o4 < 16; o4++) {
            float4 w = w4[o4];
            acc[o4*4+0] = fmaf(w.x, v, acc[o4*4+0]);
            acc[o4*4+1] = fmaf(w.y, v, acc[o4*4+1]);
            acc[o4*4+2] = fmaf(w.z, v, acc[o4*4+2]);
            acc[o4*4+3] = fmaf(w.w, v, acc[o4*4+3]);
        }
    }
    float2* O = (phase ? CF : GF) + ((size_t)(b * NPTS + m)) * NC;
    #pragma unroll
    for (int o = 0; o < NC; o++) {
        float geo = fmaf(gw[o], x, fmaf(gw[64 + o], y, gw[128 + o] * z));
        O[o] = make_float2(geo + bias2[o], acc[o] + bias2[64 + o]);
    }
}

// ---------------------------------------------------------------------------
// knn_fused4 — EXACT r16 revert (best measured: 106us).
// [r17 post-mortem: sampled-A + stride-21 el REGRESSED to 114us — looser tau
//  grew survivors ~22->~30+, inflating the serial S phase more than A saved;
//  bank-conflict counter (~137-148K cycles chip-wide) was noise all along.]
// Wave w owns cands [1024w,1024(w+1)); lane owns c[s]=cb[w*1024+s*64+lane].
//  A: full 16-slot dual-chain lane max -> shfl_xor(1,2,4) -> 64 submaxima
//     (128-cand disjoint groups covering all 8192).
//  T: tau = 16th largest of 64 submaxima -> qt_lds[q].w; >=16 witnesses.
//  B: branch-free u16 mask filter (bit-identical fma), ONE ballot/query,
//     packed (lane<<16)|mask entries.
//  S: decode -> idx list (dead mxs row) -> batch-4 gather + u64 insert.
// Grid: NQ/64 = 512 blocks x 512 threads.
// ---------------------------------------------------------------------------
__global__ __launch_bounds__(512, 4) void knn_fused4(
    const float4* __restrict__ cand, const float* __restrict__ xyz,
    int* __restrict__ idxout)
{
    __shared__ float4 qt_lds[64];            // .w = tau after T
    __shared__ float  mxs[64][ILCAP];        // A/T: submaxima; S: idx list
    __shared__ unsigned int  el[8][64][ECAP];
    __shared__ unsigned char ecnt[8][64];

    int tid = threadIdx.x;
    int lane = tid & 63, w = tid >> 6;       // w in 0..7
    int bid = blockIdx.x;
    int b = bid >> 7;                        // 128 blocks per batch
    int qb = (bid & 127) * 64;

    if (tid < 64) {
        int q = qb + tid;
        float x = xyz[(b * 3 + 0) * NPTS + q];
        float y = xyz[(b * 3 + 1) * NPTS + q];
        float z = xyz[(b * 3 + 2) * NPTS + q];
        qt_lds[tid] = make_float4(2.f * x, 2.f * y, 2.f * z, 0.f);
    }

    const float4* cb = cand + b * NPTS;
    int cbase = (w << 10) + lane;            // lane's cands: cbase + s*64
    float4 c[16];
    #pragma unroll
    for (int s = 0; s < 16; s++) c[s] = cb[cbase + (s << 6)];
    // residency force (r15-validated): compiler cannot re-load from memory
    #pragma unroll
    for (int s = 0; s < 16; s++)
        asm volatile("" : "+v"(c[s].x), "+v"(c[s].y), "+v"(c[s].z), "+v"(c[s].w));
    __syncthreads();

    // ---- A: 64 submaxima per query (dual-chain lane max + 8-lane reduce) --
    for (int qi = 0; qi < 64; ++qi) {
        float4 qt = qt_lds[qi];
        float M0 = -3.0e38f, M1 = -3.0e38f;
        #pragma unroll
        for (int s = 0; s < 16; s += 2) {
            float sc0 = fmaf(c[s].x, qt.x, fmaf(c[s].y, qt.y,
                        fmaf(c[s].z, qt.z, -c[s].w)));
            float sc1 = fmaf(c[s+1].x, qt.x, fmaf(c[s+1].y, qt.y,
                        fmaf(c[s+1].z, qt.z, -c[s+1].w)));
            M0 = fmaxf(M0, sc0);
            M1 = fmaxf(M1, sc1);
        }
        float gmx = fmaxf(M0, M1);
        gmx = fmaxf(gmx, __shfl_xor(gmx, 1));
        gmx = fmaxf(gmx, __shfl_xor(gmx, 2));
        gmx = fmaxf(gmx, __shfl_xor(gmx, 4));   // 8-lane group max
        if ((lane & 7) == 0) mxs[qi][(w << 3) + (lane >> 3)] = gmx;
    }
    __syncthreads();

    // ---- T: tau = 16th largest of 64 submaxima -> qt_lds[qq].w ----
    for (int qq = w * 8; qq < w * 8 + 8; ++qq) {
        float v = mxs[qq][lane];
        #pragma unroll
        for (int k = 2; k <= 64; k <<= 1) {
            #pragma unroll
            for (int j = k >> 1; j > 0; j >>= 1) {
                float o = __shfl_xor(v, j);
                bool up = ((lane & k) == 0);
                bool lower = ((lane & j) == 0);
                v = (up == lower) ? fminf(v, o) : fmaxf(v, o);
            }
        }
        float t = __shfl(v, 48);             // 16th largest (all lanes)
        if (lane == 0) qt_lds[qq].w = t;
    }
    __syncthreads();

    // ---- B: branch-free mask filter; ONE ballot per (wave,query) ----
    unsigned long long lmask = (1ull << lane) - 1ull;
    for (int qi = 0; qi < 64; ++qi) {
        float4 qt = qt_lds[qi];              // .w = tau
        unsigned msk = 0;
        #pragma unroll
        for (int s = 0; s < 16; s++) {
            float sc = fmaf(c[s].x, qt.x, fmaf(c[s].y, qt.y,
                       fmaf(c[s].z, qt.z, -c[s].w)));
            msk |= (sc >= qt.w) ? (1u << s) : 0u;
        }
        unsigned long long m = __ballot(msk != 0u);
        if (msk) {
            unsigned pos = (unsigned)__popcll(m & lmask);
            if (pos < ECAP)
                el[w][qi][pos] = ((unsigned)lane << 16) | msk;
        }
        if (lane == 0) {
            unsigned tot = (unsigned)__popcll(m);
            ecnt[w][qi] = (unsigned char)(tot < ECAP ? tot : ECAP);
        }
    }
    __syncthreads();

    // ---- S: decode entries -> idx list (reuse mxs row), then top-16 ----
    if (tid < 64) {
        int qi = tid;
        unsigned* il = (unsigned*)&mxs[qi][0];   // ILCAP u32 slots
        int cnt = 0;
        for (int w2 = 0; w2 < 8; w2++) {
            int cn = ecnt[w2][qi];
            for (int j = 0; j < cn; j++) {
                unsigned e = el[w2][qi][j];
                int base = (w2 << 10) + (int)(e >> 16);
                unsigned mk = e & 0xFFFFu;
                while (mk) {
                    int s = __builtin_ctz(mk);
                    mk &= mk - 1u;
                    if (cnt < ILCAP) il[cnt++] = (unsigned)(base + (s << 6));
                }
            }
        }

        float4 qt = qt_lds[qi];
        unsigned long long s16[KNN];
        #pragma unroll
        for (int j = 0; j < KNN; j++) s16[j] = 0ull;

        for (int j0 = 0; j0 < cnt; j0 += 4) {
            int li[4];
            float4 cd[4];
            #pragma unroll
            for (int t = 0; t < 4; t++) {
                int j = j0 + t;
                li[t] = (j < cnt) ? (int)il[j] : -1;
            }
            #pragma unroll
            for (int t = 0; t < 4; t++)
                if (li[t] >= 0) cd[t] = cb[li[t]];
            #pragma unroll
            for (int t = 0; t < 4; t++) {
                if (li[t] < 0) continue;
                float sc = fmaf(cd[t].x, qt.x, fmaf(cd[t].y, qt.y,
                           fmaf(cd[t].z, qt.z, -cd[t].w)));
                unsigned u = __float_as_uint(sc);
                u ^= (unsigned)((int)u >> 31) | 0x80000000u;
                unsigned long long key =
                    ((unsigned long long)u << 32) | (unsigned)(8191 - li[t]);
                if (key > s16[0]) {
                    bool cj = true;
                    #pragma unroll
                    for (int t2 = 0; t2 < KNN; t2++) {
                        bool cn2 = (t2 < KNN - 1) ? (key > s16[t2 + 1]) : false;
                        unsigned long long fv = cj ? key : s16[t2];
                        s16[t2] = cn2 ? s16[t2 + 1] : fv;
                        cj = cn2;
                    }
                }
            }
        }
        int* op = idxout + (((size_t)(b * NPTS + qb + qi)) << 4);
        #pragma unroll
        for (int j = 0; j < KNN; j++)
            op[j] = 8191 - (int)(s16[j] & 0xFFFFFFFFull);
    }
}

// ---------------------------------------------------------------------------
// fuse — unchanged (validated r2..r17):
// out[b][o][n] = max_k relu(CF.x + wd*d + GF.x) * relu(CF.y + GF.y)
// ---------------------------------------------------------------------------
__global__ __launch_bounds__(256) void fuse_kernel(
    const float* __restrict__ xyz, const float* __restrict__ Wg,
    const float4* __restrict__ cand, const float2* __restrict__ GF,
    const float2* __restrict__ CF, const int* __restrict__ idxb,
    float* __restrict__ out)
{
    __shared__ float tile[16 * 65];
    int tid = threadIdx.x;
    int o = tid & 63, w = tid >> 6;
    int b = blockIdx.x >> 9;
    int nt = (blockIdx.x & 511) << 4;
    float wd = Wg[o * 10];

    for (int i = 0; i < 4; i++) {
        int q = nt + w * 4 + i;
        size_t qb = (size_t)(b * NPTS + q);
        float qx = xyz[(b * 3 + 0) * NPTS + q];
        float qy = xyz[(b * 3 + 1) * NPTS + q];
        float qz = xyz[(b * 3 + 2) * NPTS + q];
        float2 cf = CF[qb * NC + o];
        const int* ip = idxb + qb * KNN;
        float r = 0.f;
        #pragma unroll 4
        for (int kk = 0; kk < KNN; kk++) {
            int mi = ip[kk];
            float4 c = cand[b * NPTS + mi];
            float dx = qx - c.x, dy = qy - c.y, dz = qz - c.z;
            float d = sqrtf(fmaf(dx, dx, fmaf(dy, dy, dz * dz)));
            float2 gf = GF[((size_t)(b * NPTS + mi)) * NC + o];
            float gpre = cf.x + fmaf(wd, d, gf.x);
            float fpre = cf.y + gf.y;
            r = fmaxf(r, fmaxf(gpre, 0.f) * fmaxf(fpre, 0.f));
        }
        tile[(w * 4 + i) * 65 + o] = r;
    }
    __syncthreads();
    int row = tid >> 2, cg = (tid & 3) * 4;
    float* orow = out + (size_t)(b * NC + row) * NPTS + nt + cg;
    #pragma unroll
    for (int j = 0; j < 4; j++) orow[j] = tile[(cg + j) * 65 + row];
}

extern "C" void kernel_launch(void* const* d_in, const int* in_sizes, int n_in,
                              void* d_out, int out_size, void* d_ws, size_t ws_size,
                              hipStream_t stream) {
    const float* xyz   = (const float*)d_in[0];
    const float* xyz_s = (const float*)d_in[1];
    const float* fea   = (const float*)d_in[2];
    const float* fea_s = (const float*)d_in[3];
    const float* Wg    = (const float*)d_in[4];
    const float* bg    = (const float*)d_in[5];
    const float* Wf    = (const float*)d_in[6];
    const float* bf    = (const float*)d_in[7];
    float* out = (float*)d_out;

    char* ws = (char*)d_ws;
    float4* cand = (float4*)ws;                 ws += (size_t)NQ * 16;      // 512 KB
    float2* GF   = (float2*)ws;                 ws += (size_t)NQ * NC * 8;  // 16.8 MB
    float2* CF   = (float2*)ws;                 ws += (size_t)NQ * NC * 8;  // 16.8 MB
    int*    idxb = (int*)ws;                                                // 2 MB

    // prep: 64-point / 64-thread blocks -> 2048 blocks = 8 blocks/CU
    prep_kernel<<<(NQ / 64) * 2, 64, 0, stream>>>(
        xyz, xyz_s, fea, fea_s, Wg, bg, Wf, bf, cand, GF, CF);
    knn_fused4<<<NQ / 64, 512, 0, stream>>>(cand, xyz, idxb);
    fuse_kernel<<<NB * (NPTS / 16), 256, 0, stream>>>(
        xyz, Wg, cand, GF, CF, idxb, out);
}